// Round 17
// baseline (340.470 us; speedup 1.0000x reference)
//
#include <hip/hip_runtime.h>
#include <hip/hip_bf16.h>

#define HC 128
#define NHEAD 4
#define NEG 0.2f
#define CHUNK 4096  // edges per block in staged binning

typedef unsigned int uint32;
typedef __attribute__((ext_vector_type(8))) short short8v;
typedef __attribute__((ext_vector_type(4))) float f32x4;

__device__ __forceinline__ float leaky(float v) { return v > 0.f ? v : NEG * v; }
__device__ __forceinline__ int clampi(int v, int lo, int hi) { return v < lo ? lo : (v > hi ? hi : v); }

__device__ __forceinline__ uint32 pack_bf16(float lo, float hi) {
  uint32 a = __float_as_uint(lo);
  uint32 b = __float_as_uint(hi);
  a = (a + 0x7FFFu + ((a >> 16) & 1u)) >> 16;
  b = (b + 0x7FFFu + ((b >> 16) & 1u)) & 0xFFFF0000u;
  return a | b;
}
__device__ __forceinline__ unsigned short bf16_1(float v) {
  uint32 a = __float_as_uint(v);
  return (unsigned short)((a + 0x7FFFu + ((a >> 16) & 1u)) >> 16);
}
__device__ __forceinline__ float2 unpack_bf16(uint32 u) {
  return make_float2(__uint_as_float(u << 16), __uint_as_float(u & 0xFFFF0000u));
}
__device__ __forceinline__ short8v as_s8(uint4 u) {
  union { uint4 a; short8v b; } c; c.a = u; return c.b;
}

#define WT_STRIDE 18432  // 144*128

// ---------------- utility ----------------
__global__ __launch_bounds__(256) void zero_kernel(int* __restrict__ p, int n) {
  int i = blockIdx.x * 256 + threadIdx.x;
  int stride = gridDim.x * 256;
  for (; i < n; i += stride) p[i] = 0;
}

// ================= staged CSR build (NBKT <= 256 path) =================
__global__ __launch_bounds__(256) void bincnt_lds(const int* __restrict__ dst, int* __restrict__ bcnt, int E, int n) {
  __shared__ int h[256];
  int t = threadIdx.x;
  h[t] = 0;
  __syncthreads();
  int e0 = blockIdx.x * CHUNK;
  int e1 = e0 + CHUNK < E ? e0 + CHUNK : E;
  for (int i = e0 + t; i < e1; i += 256) {
    int d = clampi(dst[i], 0, n - 1);
    atomicAdd(&h[d >> 8], 1);
  }
  __syncthreads();
  if (h[t] > 0) atomicAdd(&bcnt[t], h[t]);
}

__global__ __launch_bounds__(256) void bscan_kernel(const int* __restrict__ bcnt, int* __restrict__ bbase,
                                                    int* __restrict__ bcur, int NBKT) {
  __shared__ int part[256];
  int t = threadIdx.x;
  int c = (t < NBKT) ? bcnt[t] : 0;
  part[t] = c;
  __syncthreads();
  for (int off = 1; off < 256; off <<= 1) {
    int v = (t >= off) ? part[t - off] : 0;
    __syncthreads();
    part[t] += v;
    __syncthreads();
  }
  int excl = part[t] - c;
  if (t < NBKT) {
    bbase[t] = excl;
    bcur[t] = excl;
  }
}

__global__ __launch_bounds__(256) void binscatter_staged(const int* __restrict__ src, const int* __restrict__ dst,
                                                         int* __restrict__ bcur, int2* __restrict__ ebuf, int E, int n) {
  __shared__ int lcnt[256];
  __shared__ int lbase[256];
  int t = threadIdx.x;
  lcnt[t] = 0;
  __syncthreads();
  int e0 = blockIdx.x * CHUNK;
  int e1 = e0 + CHUNK < E ? e0 + CHUNK : E;
  for (int i = e0 + t; i < e1; i += 256) {
    int d = clampi(dst[i], 0, n - 1);
    atomicAdd(&lcnt[d >> 8], 1);
  }
  __syncthreads();
  int myc = lcnt[t];
  lbase[t] = (myc > 0) ? atomicAdd(&bcur[t], myc) : 0;
  __syncthreads();
  lcnt[t] = 0;
  __syncthreads();
  for (int i = e0 + t; i < e1; i += 256) {
    int d = clampi(dst[i], 0, n - 1);
    int s = clampi(src[i], 0, n - 1);
    int b = d >> 8;
    int pos = atomicAdd(&lcnt[b], 1);
    int p = lbase[b] + pos;
    if (p >= 0 && p < E) ebuf[p] = make_int2(s, d);
  }
}

__global__ __launch_bounds__(256) void bucket_finalize(const int2* __restrict__ ebuf, const int* __restrict__ bbase,
                                                       int* __restrict__ row_start, int* __restrict__ csr,
                                                       int NBKT, int E, int n) {
  __shared__ int cnt[256];
  __shared__ int part[256];
  __shared__ int cur[256];
  int b = blockIdx.x;
  int t = threadIdx.x;
  int start = bbase[b];
  int end = (b == NBKT - 1) ? E : bbase[b + 1];
  int d0 = b << 8;
  int ndst = n - d0; if (ndst > 256) ndst = 256;
  cnt[t] = 0;
  __syncthreads();
  for (int i = start + t; i < end; i += 256) {
    int d = ebuf[i].y - d0;
    if (d >= 0 && d < 256) atomicAdd(&cnt[d], 1);
  }
  __syncthreads();
  int c = cnt[t];
  part[t] = c;
  __syncthreads();
  for (int off = 1; off < 256; off <<= 1) {
    int v = (t >= off) ? part[t - off] : 0;
    __syncthreads();
    part[t] += v;
    __syncthreads();
  }
  int excl = part[t] - c;
  if (t < ndst) row_start[d0 + t] = start + excl;
  if (b == NBKT - 1 && t == 0) row_start[n] = E;
  cur[t] = start + excl;
  __syncthreads();
  for (int i = start + t; i < end; i += 256) {
    int2 pr = ebuf[i];
    int d = pr.y - d0;
    if (d >= 0 && d < 256) {
      int p = atomicAdd(&cur[d], 1);
      if (p >= 0 && p < E) csr[p] = pr.x;
    }
  }
}

// ================= fallback CSR build (NBKT > 256) ============
__global__ __launch_bounds__(256) void hist_kernel(const int* __restrict__ dst, int* __restrict__ cnt, int E, int n) {
  int e = blockIdx.x * 256 + threadIdx.x;
  if (e < E) atomicAdd(&cnt[clampi(dst[e], 0, n - 1)], 1);
}
__global__ __launch_bounds__(256) void scan_pass1(const int* __restrict__ cnt, int* __restrict__ blocksum, int n) {
  __shared__ int red[256];
  int t = threadIdx.x;
  int i = blockIdx.x * 256 + t;
  red[t] = i < n ? cnt[i] : 0;
  __syncthreads();
  for (int off = 128; off >= 1; off >>= 1) {
    if (t < off) red[t] += red[t + off];
    __syncthreads();
  }
  if (t == 0) blocksum[blockIdx.x] = red[0];
}
__global__ __launch_bounds__(256) void scan_pass2(const int* __restrict__ blocksum, int* __restrict__ blockpre,
                                                  int* __restrict__ row_start, int NB, int n) {
  __shared__ int part[256];
  int t = threadIdx.x;
  int chunk = (NB + 255) >> 8;
  int lo = t * chunk; if (lo > NB) lo = NB;
  int hi = lo + chunk; if (hi > NB) hi = NB;
  int s = 0;
  for (int i = lo; i < hi; ++i) s += blocksum[i];
  part[t] = s;
  __syncthreads();
  for (int off = 1; off < 256; off <<= 1) {
    int v = (t >= off) ? part[t - off] : 0;
    __syncthreads();
    part[t] += v;
    __syncthreads();
  }
  int run = part[t] - s;
  for (int i = lo; i < hi; ++i) {
    blockpre[i] = run;
    run += blocksum[i];
  }
  if (t == 255) row_start[n] = part[255];
}
__global__ __launch_bounds__(256) void scan_pass3(const int* __restrict__ cnt, const int* __restrict__ blockpre,
                                                  int* __restrict__ row_start, int* __restrict__ cursor, int n) {
  __shared__ int part[256];
  int t = threadIdx.x;
  int i = blockIdx.x * 256 + t;
  int c = i < n ? cnt[i] : 0;
  part[t] = c;
  __syncthreads();
  for (int off = 1; off < 256; off <<= 1) {
    int v = (t >= off) ? part[t - off] : 0;
    __syncthreads();
    part[t] += v;
    __syncthreads();
  }
  int excl = part[t] - c;
  if (i < n) {
    int b = blockpre[blockIdx.x] + excl;
    row_start[i] = b;
    cursor[i] = b;
  }
}
__global__ __launch_bounds__(256) void scatter_kernel(const int* __restrict__ src, const int* __restrict__ dst,
                                                      int* __restrict__ cursor, int* __restrict__ csr, int E, int n) {
  int e = blockIdx.x * 256 + threadIdx.x;
  if (e < E) {
    int d = clampi(dst[e], 0, n - 1);
    int s = clampi(src[e], 0, n - 1);
    int p = atomicAdd(&cursor[d], 1);
    if (p >= 0 && p < E) csr[p] = s;
  }
}

// ---------------- fused prep: x-pack + Wt + alpha cols + zero bcnt + zero pooled --
__global__ __launch_bounds__(256) void prep_kernel(const float* __restrict__ x, const float* __restrict__ W0,
                                                   const float* __restrict__ W1, const float* __restrict__ W2,
                                                   const float* __restrict__ as0, const float* __restrict__ as1,
                                                   const float* __restrict__ as2, const float* __restrict__ ad0,
                                                   const float* __restrict__ ad1, const float* __restrict__ ad2,
                                                   uint32* __restrict__ X16, unsigned short* __restrict__ wt,
                                                   int* __restrict__ bcnt, float* __restrict__ pooled,
                                                   long long n64, int NC, int Gp) {
  long long id = (long long)blockIdx.x * 256 + threadIdx.x;
  if (id < n64) {
    float2 v = *(const float2*)&x[id * 2];
    X16[id] = pack_bf16(v.x, v.y);
    return;
  }
  long long id2l = id - n64;
  if (id2l < 3 * 16384) {
    int id2 = (int)id2l;
    int l = id2 >> 14;
    int r = id2 & 16383;
    int k = r >> 7, nc = r & 127;
    const float* W = l == 0 ? W0 : (l == 1 ? W1 : W2);
    wt[(size_t)l * WT_STRIDE + nc * 128 + k] = bf16_1(W[r]);
    return;
  }
  id2l -= 3 * 16384;
  if (id2l < 3 * 2048) {
    int id2 = (int)id2l;
    int l = id2 >> 11;
    int r = id2 & 2047;
    int col8 = r >> 7, k = r & 127;
    const float* W = l == 0 ? W0 : (l == 1 ? W1 : W2);
    unsigned short outv = 0;
    if (col8 < 8) {
      int h = col8 & 3;
      const float* av = (col8 < 4) ? (l == 0 ? as0 : (l == 1 ? as1 : as2))
                                   : (l == 0 ? ad0 : (l == 1 ? ad1 : ad2));
      float s = 0.f;
      for (int c = 0; c < 32; ++c) s += W[k * 128 + 32 * h + c] * av[32 * h + c];
      outv = bf16_1(s);
    }
    wt[(size_t)l * WT_STRIDE + (128 + col8) * 128 + k] = outv;
    return;
  }
  id2l -= 3 * 2048;
  if (id2l < NC) {
    bcnt[id2l] = 0;
    return;
  }
  id2l -= NC;
  if (id2l < (long long)Gp * 128) pooled[id2l] = 0.f;
}

// ---------------- MFMA GEMM: 4-way column split, 1 row-group per block ----------
// Block = 256 threads = 4 waves; all waves share rows [row0, row0+16).
// wave w: nb tiles {2w, 2w+1}; wave 0 additionally alpha tile (col 128).
// D layout (verified m89): col = lane&15, row = 4*(lane>>4)+reg.
__global__ __launch_bounds__(256) void gemm_mfma(const uint32* __restrict__ X16, const unsigned short* __restrict__ Wt,
                                                 uint32* __restrict__ H16, float* __restrict__ As,
                                                 float* __restrict__ Ad, int n) {
  int t = threadIdx.x;
  int wave = t >> 6, lane = t & 63;
  int l15 = lane & 15, lg = lane >> 4;
  int row0 = blockIdx.x * 16;
  int arow = row0 + l15;
  if (arow >= n) arow = n - 1;
  const uint4* xr = (const uint4*)(X16 + (size_t)arow * 64);
  uint4 a[4];
#pragma unroll
  for (int kc = 0; kc < 4; ++kc) a[kc] = xr[kc * 4 + lg];
  const int NT = (wave == 0) ? 3 : 2;
  f32x4 acc[3];
#pragma unroll
  for (int ti = 0; ti < 3; ++ti) acc[ti] = (f32x4){0.f, 0.f, 0.f, 0.f};
#pragma unroll
  for (int kc = 0; kc < 4; ++kc) {
    uint4 b[3];
#pragma unroll
    for (int ti = 0; ti < 3; ++ti) {
      if (ti < NT) {
        int basecol = (ti < 2) ? (2 * wave + ti) * 16 : 128;
        b[ti] = *(const uint4*)(Wt + (size_t)(basecol + l15) * 128 + kc * 32 + lg * 8);
      }
    }
#pragma unroll
    for (int ti = 0; ti < 3; ++ti)
      if (ti < NT) acc[ti] = __builtin_amdgcn_mfma_f32_16x16x32_bf16(as_s8(a[kc]), as_s8(b[ti]), acc[ti], 0, 0, 0);
  }
#pragma unroll
  for (int r = 0; r < 4; ++r) {
    int gr = row0 + lg * 4 + r;
    bool ok = gr < n;
#pragma unroll
    for (int ti = 0; ti < 2; ++ti) {
      int nb = 2 * wave + ti;
      float mine = acc[ti][r];
      float other = __shfl_xor(mine, 1);
      if (ok && (lane & 1) == 0) H16[(size_t)gr * 64 + nb * 8 + (l15 >> 1)] = pack_bf16(mine, other);
    }
    if (wave == 0) {
      float av = acc[2][r];
      if (ok && l15 < 4) As[gr * 4 + l15] = av;
      if (ok && l15 >= 4 && l15 < 8) Ad[gr * 4 + (l15 - 4)] = av;
    }
  }
}

// ---------------- fused softmax + aggregation (wave per node, 16-deep MLP) -------
// POOL=false: write bf16 X16 for next layer. POOL=true (last layer): relu+bias
// then atomicAdd into pooled[batch[node]] (2 float adds per lane).
template <bool POOL>
__global__ __launch_bounds__(256) void agg_kernel(const uint32* __restrict__ H16, const float* __restrict__ As,
                                                  const float* __restrict__ Ad, const int* __restrict__ row_start,
                                                  const int* __restrict__ csr, const float* __restrict__ bias,
                                                  const int* __restrict__ batch, void* __restrict__ outv,
                                                  int n, int G) {
  int wid = (blockIdx.x * 256 + threadIdx.x) >> 6;
  int lane = threadIdx.x & 63;
  if (wid >= n) return;
  int base = row_start[wid];
  int deg = row_start[wid + 1] - base;
  if (deg < 0) deg = 0;
  int hsel = lane >> 4;
  float adsel = Ad[wid * 4 + hsel];
  float pself = __expf(leaky(As[wid * 4 + hsel] + adsel));
  float2 hv = unpack_bf16(H16[(size_t)wid * 64 + lane]);
  float den = pself;
  float acc0 = pself * hv.x, acc1 = pself * hv.y;
  for (int chunk = 0; chunk < deg; chunk += 64) {
    int j = chunk + lane;
    int smine = (j < deg) ? csr[base + j] : 0;  // csr pre-clamped at build
    int cnt_ = deg - chunk; if (cnt_ > 64) cnt_ = 64;
#pragma unroll
    for (int k = 0; k < 4; ++k) {
      if (k * 16 >= cnt_) break;  // wave-uniform
      // alpha for this 16-edge group: slot (lane&15), head (lane>>4)
      float pmk;
      {
        int slot = k * 16 + (lane & 15);
        int sk = __shfl(smine, slot);
        float e = As[sk * 4 + hsel];
        pmk = (slot < cnt_) ? __expf(leaky(e + adsel)) : 0.f;
      }
      int ss[16];
      uint32 h2[16];
#pragma unroll
      for (int i = 0; i < 16; ++i) ss[i] = __shfl(smine, k * 16 + i);
#pragma unroll
      for (int i = 0; i < 16; ++i) h2[i] = H16[(size_t)((uint32)ss[i] * 64 + lane)];
#pragma unroll
      for (int i = 0; i < 16; ++i) {
        float aw = __shfl(pmk, (lane & 48) + i);  // 0 when edge i inactive
        float2 hh = unpack_bf16(h2[i]);
        den += aw;
        acc0 += aw * hh.x;
        acc1 += aw * hh.y;
      }
    }
  }
  float inv = 1.f / den;
  float2 bv = *(const float2*)&bias[2 * lane];
  float r0v = fmaxf(acc0 * inv + bv.x, 0.f);
  float r1v = fmaxf(acc1 * inv + bv.y, 0.f);
  if constexpr (POOL) {
    int g = clampi(batch[wid], 0, G - 1);
    float* pooled = (float*)outv;
    atomicAdd(&pooled[g * 128 + 2 * lane], r0v);
    atomicAdd(&pooled[g * 128 + 2 * lane + 1], r1v);
  } else {
    ((uint32*)outv)[(size_t)wid * 64 + lane] = pack_bf16(r0v, r1v);
  }
}

// ---------------- logits: pooled @ Wh + bh ----------------
__global__ __launch_bounds__(64) void logits_kernel(const float* __restrict__ pooled, const float* __restrict__ Wh,
                                                    const float* __restrict__ bh, float* __restrict__ out) {
  int g = blockIdx.x, lane = threadIdx.x;
  float p0 = pooled[g * 128 + lane];
  float p1 = pooled[g * 128 + lane + 64];
  for (int o = 0; o < 10; ++o) {
    float v = p0 * Wh[lane * 10 + o] + p1 * Wh[(lane + 64) * 10 + o];
#pragma unroll
    for (int off = 32; off >= 1; off >>= 1) v += __shfl_xor(v, off);
    if (lane == 0) out[g * 10 + o] = v + bh[o];
  }
}

extern "C" void kernel_launch(void* const* d_in, const int* in_sizes, int n_in,
                              void* d_out, int out_size, void* d_ws, size_t ws_size,
                              hipStream_t stream) {
  const float *x, *Wl[3], *asr[3], *adr[3], *bias[3], *Wh, *bh;
  const int *edge_index, *batch;
  long long E_ll;
  if (n_in >= 17) {
    x = (const float*)d_in[0];
    for (int l = 0; l < 3; ++l) {
      Wl[l] = (const float*)d_in[1 + l];
      asr[l] = (const float*)d_in[4 + l];
      adr[l] = (const float*)d_in[7 + l];
      bias[l] = (const float*)d_in[10 + l];
    }
    Wh = (const float*)d_in[13];
    bh = (const float*)d_in[14];
    edge_index = (const int*)d_in[15];
    batch = (const int*)d_in[16];
    E_ll = (long long)in_sizes[15] / 2;
  } else if (n_in >= 9) {
    x = (const float*)d_in[0];
    const float* Wc = (const float*)d_in[1];
    const float* ac = (const float*)d_in[2];
    const float* dc = (const float*)d_in[3];
    const float* bc = (const float*)d_in[4];
    for (int l = 0; l < 3; ++l) {
      Wl[l] = Wc + (size_t)l * HC * HC;
      asr[l] = ac + (size_t)l * HC;
      adr[l] = dc + (size_t)l * HC;
      bias[l] = bc + (size_t)l * HC;
    }
    Wh = (const float*)d_in[5];
    bh = (const float*)d_in[6];
    edge_index = (const int*)d_in[7];
    batch = (const int*)d_in[8];
    E_ll = (long long)in_sizes[7] / 2;
  } else {
    zero_kernel<<<(out_size + 255) / 256, 256, 0, stream>>>((int*)d_out, out_size);
    return;
  }
  int N = in_sizes[0] / HC;
  int G = out_size / 10;
  if (N <= 0 || G <= 0 || E_ll <= 0 || E_ll > (1LL << 30)) {
    zero_kernel<<<(out_size + 255) / 256, 256, 0, stream>>>((int*)d_out, out_size);
    return;
  }
  int E = (int)E_ll;
  int NBKT = (N + 255) >> 8;
  int NB = (N + 255) / 256;
  bool staged = (NBKT <= 256);

  char* w = (char*)d_ws;
  size_t off = 0;
  auto take = [&](size_t bytes) -> char* {
    char* p = w + off;
    off = (off + bytes + 511) & ~(size_t)511;
    return p;
  };
  uint32* H16 = (uint32*)take((size_t)N * 64 * 4);
  uint32* X16 = (uint32*)take((size_t)N * 64 * 4);
  uint32* Xa = (uint32*)take((size_t)N * 64 * 4);  // bf16 x staging (layer-0 input)
  float* As = (float*)take((size_t)N * NHEAD * 4);
  float* Ad = (float*)take((size_t)N * NHEAD * 4);
  int* row_start = (int*)take((size_t)(N + 1) * 4);
  int* csr = (int*)take((size_t)E * 4);
  int2* ebuf = (int2*)take((size_t)E * 8);
  int* bcnt = (int*)take(256 * 4);
  int* bbase = (int*)take(256 * 4);
  int* bcur = (int*)take(256 * 4);
  int* cnt = (int*)take((size_t)N * 4);       // fallback
  int* cursor = (int*)take((size_t)N * 4);    // fallback
  int* blocksum = (int*)take((size_t)NB * 4); // fallback
  int* blockpre = (int*)take((size_t)NB * 4); // fallback
  float* pooled = (float*)take((size_t)G * HC * 4);
  unsigned short* wt16 = (unsigned short*)take((size_t)3 * WT_STRIDE * 2);

  if (off > ws_size) {
    zero_kernel<<<(out_size + 255) / 256, 256, 0, stream>>>((int*)d_out, out_size);
    return;
  }

  const int* esrc = edge_index;
  const int* edst = edge_index + E;

  long long n64 = (long long)N * 64;
  long long prep_items = n64 + 3 * 16384 + 3 * 2048 + 256 + (long long)G * 128;
  prep_kernel<<<(int)((prep_items + 255) / 256), 256, 0, stream>>>(
      x, Wl[0], Wl[1], Wl[2], asr[0], asr[1], asr[2], adr[0], adr[1], adr[2],
      Xa, wt16, bcnt, pooled, n64, 256, G);

  int echunks = (E + CHUNK - 1) / CHUNK;
  if (staged) {
    bincnt_lds<<<echunks, 256, 0, stream>>>(edst, bcnt, E, N);
    bscan_kernel<<<1, 256, 0, stream>>>(bcnt, bbase, bcur, NBKT);
    binscatter_staged<<<echunks, 256, 0, stream>>>(esrc, edst, bcur, ebuf, E, N);
    bucket_finalize<<<NBKT, 256, 0, stream>>>(ebuf, bbase, row_start, csr, NBKT, E, N);
  } else {
    zero_kernel<<<(N + 255) / 256, 256, 0, stream>>>(cnt, N);
    hist_kernel<<<(E + 255) / 256, 256, 0, stream>>>(edst, cnt, E, N);
    scan_pass1<<<NB, 256, 0, stream>>>(cnt, blocksum, N);
    scan_pass2<<<1, 256, 0, stream>>>(blocksum, blockpre, row_start, NB, N);
    scan_pass3<<<NB, 256, 0, stream>>>(cnt, blockpre, row_start, cursor, N);
    scatter_kernel<<<(E + 255) / 256, 256, 0, stream>>>(esrc, edst, cursor, csr, E, N);
  }

  int gemm_grid = (N + 15) / 16;
  int agg_grid = (N + 3) / 4;

  // layer 0
  gemm_mfma<<<gemm_grid, 256, 0, stream>>>(Xa, wt16, H16, As, Ad, N);
  agg_kernel<false><<<agg_grid, 256, 0, stream>>>(H16, As, Ad, row_start, csr, bias[0], batch, X16, N, G);
  // layer 1
  gemm_mfma<<<gemm_grid, 256, 0, stream>>>(X16, wt16 + WT_STRIDE, H16, As, Ad, N);
  agg_kernel<false><<<agg_grid, 256, 0, stream>>>(H16, As, Ad, row_start, csr, bias[1], batch, X16, N, G);
  // layer 2: aggregate + relu + pool directly into `pooled`
  gemm_mfma<<<gemm_grid, 256, 0, stream>>>(X16, wt16 + 2 * WT_STRIDE, H16, As, Ad, N);
  agg_kernel<true><<<agg_grid, 256, 0, stream>>>(H16, As, Ad, row_start, csr, bias[2], batch, pooled, N, G);

  logits_kernel<<<G, 64, 0, stream>>>(pooled, Wh, bh, (float*)d_out);
}

// Round 18
// 267.043 us; speedup vs baseline: 1.2750x; 1.2750x over previous
//
#include <hip/hip_runtime.h>
#include <hip/hip_bf16.h>

#define HC 128
#define NHEAD 4
#define NEG 0.2f
#define CHUNK 4096  // edges per block in staged binning

typedef unsigned int uint32;
typedef __attribute__((ext_vector_type(8))) short short8v;
typedef __attribute__((ext_vector_type(4))) float f32x4;

__device__ __forceinline__ float leaky(float v) { return v > 0.f ? v : NEG * v; }
__device__ __forceinline__ int clampi(int v, int lo, int hi) { return v < lo ? lo : (v > hi ? hi : v); }

__device__ __forceinline__ uint32 pack_bf16(float lo, float hi) {
  uint32 a = __float_as_uint(lo);
  uint32 b = __float_as_uint(hi);
  a = (a + 0x7FFFu + ((a >> 16) & 1u)) >> 16;
  b = (b + 0x7FFFu + ((b >> 16) & 1u)) & 0xFFFF0000u;
  return a | b;
}
__device__ __forceinline__ unsigned short bf16_1(float v) {
  uint32 a = __float_as_uint(v);
  return (unsigned short)((a + 0x7FFFu + ((a >> 16) & 1u)) >> 16);
}
__device__ __forceinline__ float2 unpack_bf16(uint32 u) {
  return make_float2(__uint_as_float(u << 16), __uint_as_float(u & 0xFFFF0000u));
}
__device__ __forceinline__ short8v as_s8(uint4 u) {
  union { uint4 a; short8v b; } c; c.a = u; return c.b;
}

#define WT_STRIDE 18432  // 144*128

// ---------------- utility ----------------
__global__ __launch_bounds__(256) void zero_kernel(int* __restrict__ p, int n) {
  int i = blockIdx.x * 256 + threadIdx.x;
  int stride = gridDim.x * 256;
  for (; i < n; i += stride) p[i] = 0;
}

// ================= staged CSR build (NBKT <= 256 path) =================
__global__ __launch_bounds__(256) void bincnt_lds(const int* __restrict__ dst, int* __restrict__ bcnt, int E, int n) {
  __shared__ int h[256];
  int t = threadIdx.x;
  h[t] = 0;
  __syncthreads();
  int e0 = blockIdx.x * CHUNK;
  int e1 = e0 + CHUNK < E ? e0 + CHUNK : E;
  for (int i = e0 + t; i < e1; i += 256) {
    int d = clampi(dst[i], 0, n - 1);
    atomicAdd(&h[d >> 8], 1);
  }
  __syncthreads();
  if (h[t] > 0) atomicAdd(&bcnt[t], h[t]);
}

__global__ __launch_bounds__(256) void bscan_kernel(const int* __restrict__ bcnt, int* __restrict__ bbase,
                                                    int* __restrict__ bcur, int NBKT) {
  __shared__ int part[256];
  int t = threadIdx.x;
  int c = (t < NBKT) ? bcnt[t] : 0;
  part[t] = c;
  __syncthreads();
  for (int off = 1; off < 256; off <<= 1) {
    int v = (t >= off) ? part[t - off] : 0;
    __syncthreads();
    part[t] += v;
    __syncthreads();
  }
  int excl = part[t] - c;
  if (t < NBKT) {
    bbase[t] = excl;
    bcur[t] = excl;
  }
}

__global__ __launch_bounds__(256) void binscatter_staged(const int* __restrict__ src, const int* __restrict__ dst,
                                                         int* __restrict__ bcur, int2* __restrict__ ebuf, int E, int n) {
  __shared__ int lcnt[256];
  __shared__ int lbase[256];
  int t = threadIdx.x;
  lcnt[t] = 0;
  __syncthreads();
  int e0 = blockIdx.x * CHUNK;
  int e1 = e0 + CHUNK < E ? e0 + CHUNK : E;
  for (int i = e0 + t; i < e1; i += 256) {
    int d = clampi(dst[i], 0, n - 1);
    atomicAdd(&lcnt[d >> 8], 1);
  }
  __syncthreads();
  int myc = lcnt[t];
  lbase[t] = (myc > 0) ? atomicAdd(&bcur[t], myc) : 0;
  __syncthreads();
  lcnt[t] = 0;
  __syncthreads();
  for (int i = e0 + t; i < e1; i += 256) {
    int d = clampi(dst[i], 0, n - 1);
    int s = clampi(src[i], 0, n - 1);
    int b = d >> 8;
    int pos = atomicAdd(&lcnt[b], 1);
    int p = lbase[b] + pos;
    if (p >= 0 && p < E) ebuf[p] = make_int2(s, d);
  }
}

__global__ __launch_bounds__(256) void bucket_finalize(const int2* __restrict__ ebuf, const int* __restrict__ bbase,
                                                       int* __restrict__ row_start, int* __restrict__ csr,
                                                       int NBKT, int E, int n) {
  __shared__ int cnt[256];
  __shared__ int part[256];
  __shared__ int cur[256];
  int b = blockIdx.x;
  int t = threadIdx.x;
  int start = bbase[b];
  int end = (b == NBKT - 1) ? E : bbase[b + 1];
  int d0 = b << 8;
  int ndst = n - d0; if (ndst > 256) ndst = 256;
  cnt[t] = 0;
  __syncthreads();
  for (int i = start + t; i < end; i += 256) {
    int d = ebuf[i].y - d0;
    if (d >= 0 && d < 256) atomicAdd(&cnt[d], 1);
  }
  __syncthreads();
  int c = cnt[t];
  part[t] = c;
  __syncthreads();
  for (int off = 1; off < 256; off <<= 1) {
    int v = (t >= off) ? part[t - off] : 0;
    __syncthreads();
    part[t] += v;
    __syncthreads();
  }
  int excl = part[t] - c;
  if (t < ndst) row_start[d0 + t] = start + excl;
  if (b == NBKT - 1 && t == 0) row_start[n] = E;
  cur[t] = start + excl;
  __syncthreads();
  for (int i = start + t; i < end; i += 256) {
    int2 pr = ebuf[i];
    int d = pr.y - d0;
    if (d >= 0 && d < 256) {
      int p = atomicAdd(&cur[d], 1);
      if (p >= 0 && p < E) csr[p] = pr.x;
    }
  }
}

// ================= fallback CSR build (NBKT > 256) ============
__global__ __launch_bounds__(256) void hist_kernel(const int* __restrict__ dst, int* __restrict__ cnt, int E, int n) {
  int e = blockIdx.x * 256 + threadIdx.x;
  if (e < E) atomicAdd(&cnt[clampi(dst[e], 0, n - 1)], 1);
}
__global__ __launch_bounds__(256) void scan_pass1(const int* __restrict__ cnt, int* __restrict__ blocksum, int n) {
  __shared__ int red[256];
  int t = threadIdx.x;
  int i = blockIdx.x * 256 + t;
  red[t] = i < n ? cnt[i] : 0;
  __syncthreads();
  for (int off = 128; off >= 1; off >>= 1) {
    if (t < off) red[t] += red[t + off];
    __syncthreads();
  }
  if (t == 0) blocksum[blockIdx.x] = red[0];
}
__global__ __launch_bounds__(256) void scan_pass2(const int* __restrict__ blocksum, int* __restrict__ blockpre,
                                                  int* __restrict__ row_start, int NB, int n) {
  __shared__ int part[256];
  int t = threadIdx.x;
  int chunk = (NB + 255) >> 8;
  int lo = t * chunk; if (lo > NB) lo = NB;
  int hi = lo + chunk; if (hi > NB) hi = NB;
  int s = 0;
  for (int i = lo; i < hi; ++i) s += blocksum[i];
  part[t] = s;
  __syncthreads();
  for (int off = 1; off < 256; off <<= 1) {
    int v = (t >= off) ? part[t - off] : 0;
    __syncthreads();
    part[t] += v;
    __syncthreads();
  }
  int run = part[t] - s;
  for (int i = lo; i < hi; ++i) {
    blockpre[i] = run;
    run += blocksum[i];
  }
  if (t == 255) row_start[n] = part[255];
}
__global__ __launch_bounds__(256) void scan_pass3(const int* __restrict__ cnt, const int* __restrict__ blockpre,
                                                  int* __restrict__ row_start, int* __restrict__ cursor, int n) {
  __shared__ int part[256];
  int t = threadIdx.x;
  int i = blockIdx.x * 256 + t;
  int c = i < n ? cnt[i] : 0;
  part[t] = c;
  __syncthreads();
  for (int off = 1; off < 256; off <<= 1) {
    int v = (t >= off) ? part[t - off] : 0;
    __syncthreads();
    part[t] += v;
    __syncthreads();
  }
  int excl = part[t] - c;
  if (i < n) {
    int b = blockpre[blockIdx.x] + excl;
    row_start[i] = b;
    cursor[i] = b;
  }
}
__global__ __launch_bounds__(256) void scatter_kernel(const int* __restrict__ src, const int* __restrict__ dst,
                                                      int* __restrict__ cursor, int* __restrict__ csr, int E, int n) {
  int e = blockIdx.x * 256 + threadIdx.x;
  if (e < E) {
    int d = clampi(dst[e], 0, n - 1);
    int s = clampi(src[e], 0, n - 1);
    int p = atomicAdd(&cursor[d], 1);
    if (p >= 0 && p < E) csr[p] = s;
  }
}

// ---------------- fused prep: x-pack + Wt + alpha cols + zero bcnt + out=bh ------
__global__ __launch_bounds__(256) void prep_kernel(const float* __restrict__ x, const float* __restrict__ W0,
                                                   const float* __restrict__ W1, const float* __restrict__ W2,
                                                   const float* __restrict__ as0, const float* __restrict__ as1,
                                                   const float* __restrict__ as2, const float* __restrict__ ad0,
                                                   const float* __restrict__ ad1, const float* __restrict__ ad2,
                                                   const float* __restrict__ bh, uint32* __restrict__ X16,
                                                   unsigned short* __restrict__ wt, int* __restrict__ bcnt,
                                                   float* __restrict__ outp, long long n64, int NC, int Gp) {
  long long id = (long long)blockIdx.x * 256 + threadIdx.x;
  if (id < n64) {
    float2 v = *(const float2*)&x[id * 2];
    X16[id] = pack_bf16(v.x, v.y);
    return;
  }
  long long id2l = id - n64;
  if (id2l < 3 * 16384) {
    int id2 = (int)id2l;
    int l = id2 >> 14;
    int r = id2 & 16383;
    int k = r >> 7, nc = r & 127;
    const float* W = l == 0 ? W0 : (l == 1 ? W1 : W2);
    wt[(size_t)l * WT_STRIDE + nc * 128 + k] = bf16_1(W[r]);
    return;
  }
  id2l -= 3 * 16384;
  if (id2l < 3 * 2048) {
    int id2 = (int)id2l;
    int l = id2 >> 11;
    int r = id2 & 2047;
    int col8 = r >> 7, k = r & 127;
    const float* W = l == 0 ? W0 : (l == 1 ? W1 : W2);
    unsigned short outv = 0;
    if (col8 < 8) {
      int h = col8 & 3;
      const float* av = (col8 < 4) ? (l == 0 ? as0 : (l == 1 ? as1 : as2))
                                   : (l == 0 ? ad0 : (l == 1 ? ad1 : ad2));
      float s = 0.f;
      for (int c = 0; c < 32; ++c) s += W[k * 128 + 32 * h + c] * av[32 * h + c];
      outv = bf16_1(s);
    }
    wt[(size_t)l * WT_STRIDE + (128 + col8) * 128 + k] = outv;
    return;
  }
  id2l -= 3 * 2048;
  if (id2l < NC) {
    bcnt[id2l] = 0;
    return;
  }
  id2l -= NC;
  if (id2l < (long long)Gp * 10) outp[id2l] = bh[id2l % 10];
}

// ---------------- MFMA GEMM: 4-way column split, 1 row-group per block ----------
// Block = 256 threads = 4 waves; all waves share rows [row0, row0+16).
// wave w: nb tiles {2w, 2w+1}; wave 0 additionally alpha tile (col 128).
// D layout (verified m89): col = lane&15, row = 4*(lane>>4)+reg.
__global__ __launch_bounds__(256) void gemm_mfma(const uint32* __restrict__ X16, const unsigned short* __restrict__ Wt,
                                                 uint32* __restrict__ H16, float* __restrict__ As,
                                                 float* __restrict__ Ad, int n) {
  int t = threadIdx.x;
  int wave = t >> 6, lane = t & 63;
  int l15 = lane & 15, lg = lane >> 4;
  int row0 = blockIdx.x * 16;
  int arow = row0 + l15;
  if (arow >= n) arow = n - 1;
  const uint4* xr = (const uint4*)(X16 + (size_t)arow * 64);
  uint4 a[4];
#pragma unroll
  for (int kc = 0; kc < 4; ++kc) a[kc] = xr[kc * 4 + lg];
  const int NT = (wave == 0) ? 3 : 2;
  f32x4 acc[3];
#pragma unroll
  for (int ti = 0; ti < 3; ++ti) acc[ti] = (f32x4){0.f, 0.f, 0.f, 0.f};
#pragma unroll
  for (int kc = 0; kc < 4; ++kc) {
    uint4 b[3];
#pragma unroll
    for (int ti = 0; ti < 3; ++ti) {
      if (ti < NT) {
        int basecol = (ti < 2) ? (2 * wave + ti) * 16 : 128;
        b[ti] = *(const uint4*)(Wt + (size_t)(basecol + l15) * 128 + kc * 32 + lg * 8);
      }
    }
#pragma unroll
    for (int ti = 0; ti < 3; ++ti)
      if (ti < NT) acc[ti] = __builtin_amdgcn_mfma_f32_16x16x32_bf16(as_s8(a[kc]), as_s8(b[ti]), acc[ti], 0, 0, 0);
  }
#pragma unroll
  for (int r = 0; r < 4; ++r) {
    int gr = row0 + lg * 4 + r;
    bool ok = gr < n;
#pragma unroll
    for (int ti = 0; ti < 2; ++ti) {
      int nb = 2 * wave + ti;
      float mine = acc[ti][r];
      float other = __shfl_xor(mine, 1);
      if (ok && (lane & 1) == 0) H16[(size_t)gr * 64 + nb * 8 + (l15 >> 1)] = pack_bf16(mine, other);
    }
    if (wave == 0) {
      float av = acc[2][r];
      if (ok && l15 < 4) As[gr * 4 + l15] = av;
      if (ok && l15 >= 4 && l15 < 8) Ad[gr * 4 + (l15 - 4)] = av;
    }
  }
}

// ---------------- fused softmax + aggregation (wave per node, 16-deep MLP) -------
template <bool OUTFP32>
__global__ __launch_bounds__(256) void agg_kernel(const uint32* __restrict__ H16, const float* __restrict__ As,
                                                  const float* __restrict__ Ad, const int* __restrict__ row_start,
                                                  const int* __restrict__ csr, const float* __restrict__ bias,
                                                  void* __restrict__ outv, int n) {
  int wid = (blockIdx.x * 256 + threadIdx.x) >> 6;
  int lane = threadIdx.x & 63;
  if (wid >= n) return;
  int base = row_start[wid];
  int deg = row_start[wid + 1] - base;
  if (deg < 0) deg = 0;
  int hsel = lane >> 4;
  float adsel = Ad[wid * 4 + hsel];
  float pself = __expf(leaky(As[wid * 4 + hsel] + adsel));
  float2 hv = unpack_bf16(H16[(size_t)wid * 64 + lane]);
  float den = pself;
  float acc0 = pself * hv.x, acc1 = pself * hv.y;
  for (int chunk = 0; chunk < deg; chunk += 64) {
    int j = chunk + lane;
    int smine = (j < deg) ? csr[base + j] : 0;  // csr pre-clamped at build
    int cnt_ = deg - chunk; if (cnt_ > 64) cnt_ = 64;
#pragma unroll
    for (int k = 0; k < 4; ++k) {
      if (k * 16 >= cnt_) break;  // wave-uniform
      float pmk;
      {
        int slot = k * 16 + (lane & 15);
        int sk = __shfl(smine, slot);
        float e = As[sk * 4 + hsel];
        pmk = (slot < cnt_) ? __expf(leaky(e + adsel)) : 0.f;
      }
      int ss[16];
      uint32 h2[16];
#pragma unroll
      for (int i = 0; i < 16; ++i) ss[i] = __shfl(smine, k * 16 + i);
#pragma unroll
      for (int i = 0; i < 16; ++i) h2[i] = H16[(size_t)((uint32)ss[i] * 64 + lane)];
#pragma unroll
      for (int i = 0; i < 16; ++i) {
        float aw = __shfl(pmk, (lane & 48) + i);  // 0 when edge i inactive
        float2 hh = unpack_bf16(h2[i]);
        den += aw;
        acc0 += aw * hh.x;
        acc1 += aw * hh.y;
      }
    }
  }
  float inv = 1.f / den;
  float2 bv = *(const float2*)&bias[2 * lane];
  float r0v = fmaxf(acc0 * inv + bv.x, 0.f);
  float r1v = fmaxf(acc1 * inv + bv.y, 0.f);
  if constexpr (OUTFP32) {
    ((float2*)outv)[(size_t)wid * 64 + lane] = make_float2(r0v, r1v);
  } else {
    ((uint32*)outv)[(size_t)wid * 64 + lane] = pack_bf16(r0v, r1v);
  }
}

// ---------------- fused pooling + logits (batch sorted; run-length flush) --------
// out must be pre-initialized to bh (done in prep).
__global__ __launch_bounds__(128) void pool_logits(const float* __restrict__ X, const int* __restrict__ batch,
                                                   const float* __restrict__ Wh, float* __restrict__ out,
                                                   int n, int G) {
  __shared__ float red[128];
  int c = threadIdx.x;
  int n0 = blockIdx.x * 64;
  if (n0 >= n) return;
  int end = n0 + 64 < n ? n0 + 64 : n;
  int curg = clampi(batch[n0], 0, G - 1);
  float acc = 0.f;
  for (int i = n0; i <= end; ++i) {
    int g = (i < end) ? clampi(batch[i], 0, G - 1) : -1;
    if (g != curg) {
      red[c] = acc;
      __syncthreads();
      if (c < 10) {
        float s = 0.f;
#pragma unroll 16
        for (int cc = 0; cc < 128; ++cc) s += red[cc] * Wh[cc * 10 + c];
        atomicAdd(&out[curg * 10 + c], s);
      }
      __syncthreads();
      acc = 0.f;
      curg = g;
    }
    if (i < end) acc += X[(size_t)i * 128 + c];
  }
}

extern "C" void kernel_launch(void* const* d_in, const int* in_sizes, int n_in,
                              void* d_out, int out_size, void* d_ws, size_t ws_size,
                              hipStream_t stream) {
  const float *x, *Wl[3], *asr[3], *adr[3], *bias[3], *Wh, *bh;
  const int *edge_index, *batch;
  long long E_ll;
  if (n_in >= 17) {
    x = (const float*)d_in[0];
    for (int l = 0; l < 3; ++l) {
      Wl[l] = (const float*)d_in[1 + l];
      asr[l] = (const float*)d_in[4 + l];
      adr[l] = (const float*)d_in[7 + l];
      bias[l] = (const float*)d_in[10 + l];
    }
    Wh = (const float*)d_in[13];
    bh = (const float*)d_in[14];
    edge_index = (const int*)d_in[15];
    batch = (const int*)d_in[16];
    E_ll = (long long)in_sizes[15] / 2;
  } else if (n_in >= 9) {
    x = (const float*)d_in[0];
    const float* Wc = (const float*)d_in[1];
    const float* ac = (const float*)d_in[2];
    const float* dc = (const float*)d_in[3];
    const float* bc = (const float*)d_in[4];
    for (int l = 0; l < 3; ++l) {
      Wl[l] = Wc + (size_t)l * HC * HC;
      asr[l] = ac + (size_t)l * HC;
      adr[l] = dc + (size_t)l * HC;
      bias[l] = bc + (size_t)l * HC;
    }
    Wh = (const float*)d_in[5];
    bh = (const float*)d_in[6];
    edge_index = (const int*)d_in[7];
    batch = (const int*)d_in[8];
    E_ll = (long long)in_sizes[7] / 2;
  } else {
    zero_kernel<<<(out_size + 255) / 256, 256, 0, stream>>>((int*)d_out, out_size);
    return;
  }
  int N = in_sizes[0] / HC;
  int G = out_size / 10;
  if (N <= 0 || G <= 0 || E_ll <= 0 || E_ll > (1LL << 30)) {
    zero_kernel<<<(out_size + 255) / 256, 256, 0, stream>>>((int*)d_out, out_size);
    return;
  }
  int E = (int)E_ll;
  int NBKT = (N + 255) >> 8;
  int NB = (N + 255) / 256;
  bool staged = (NBKT <= 256);

  char* w = (char*)d_ws;
  size_t off = 0;
  auto take = [&](size_t bytes) -> char* {
    char* p = w + off;
    off = (off + bytes + 511) & ~(size_t)511;
    return p;
  };
  uint32* H16 = (uint32*)take((size_t)N * 64 * 4);
  uint32* X16 = (uint32*)take((size_t)N * 64 * 4);
  float* bufQ = (float*)take((size_t)N * HC * 4);   // layer-2 fp32 output
  uint32* Xa = (uint32*)bufQ;                        // aliased: bf16 x (consumed before bufQ written)
  float* As = (float*)take((size_t)N * NHEAD * 4);
  float* Ad = (float*)take((size_t)N * NHEAD * 4);
  int* row_start = (int*)take((size_t)(N + 1) * 4);
  int* csr = (int*)take((size_t)E * 4);
  int2* ebuf = (int2*)take((size_t)E * 8);
  int* bcnt = (int*)take(256 * 4);
  int* bbase = (int*)take(256 * 4);
  int* bcur = (int*)take(256 * 4);
  int* cnt = (int*)take((size_t)N * 4);       // fallback
  int* cursor = (int*)take((size_t)N * 4);    // fallback
  int* blocksum = (int*)take((size_t)NB * 4); // fallback
  int* blockpre = (int*)take((size_t)NB * 4); // fallback
  unsigned short* wt16 = (unsigned short*)take((size_t)3 * WT_STRIDE * 2);

  if (off > ws_size) {
    zero_kernel<<<(out_size + 255) / 256, 256, 0, stream>>>((int*)d_out, out_size);
    return;
  }

  const int* esrc = edge_index;
  const int* edst = edge_index + E;

  long long n64 = (long long)N * 64;
  long long prep_items = n64 + 3 * 16384 + 3 * 2048 + 256 + (long long)G * 10;
  prep_kernel<<<(int)((prep_items + 255) / 256), 256, 0, stream>>>(
      x, Wl[0], Wl[1], Wl[2], asr[0], asr[1], asr[2], adr[0], adr[1], adr[2], bh,
      Xa, wt16, bcnt, (float*)d_out, n64, 256, G);

  int echunks = (E + CHUNK - 1) / CHUNK;
  if (staged) {
    bincnt_lds<<<echunks, 256, 0, stream>>>(edst, bcnt, E, N);
    bscan_kernel<<<1, 256, 0, stream>>>(bcnt, bbase, bcur, NBKT);
    binscatter_staged<<<echunks, 256, 0, stream>>>(esrc, edst, bcur, ebuf, E, N);
    bucket_finalize<<<NBKT, 256, 0, stream>>>(ebuf, bbase, row_start, csr, NBKT, E, N);
  } else {
    zero_kernel<<<(N + 255) / 256, 256, 0, stream>>>(cnt, N);
    hist_kernel<<<(E + 255) / 256, 256, 0, stream>>>(edst, cnt, E, N);
    scan_pass1<<<NB, 256, 0, stream>>>(cnt, blocksum, N);
    scan_pass2<<<1, 256, 0, stream>>>(blocksum, blockpre, row_start, NB, N);
    scan_pass3<<<NB, 256, 0, stream>>>(cnt, blockpre, row_start, cursor, N);
    scatter_kernel<<<(E + 255) / 256, 256, 0, stream>>>(esrc, edst, cursor, csr, E, N);
  }

  int gemm_grid = (N + 15) / 16;
  int agg_grid = (N + 3) / 4;

  // layer 0
  gemm_mfma<<<gemm_grid, 256, 0, stream>>>(Xa, wt16, H16, As, Ad, N);
  agg_kernel<false><<<agg_grid, 256, 0, stream>>>(H16, As, Ad, row_start, csr, bias[0], X16, N);
  // layer 1
  gemm_mfma<<<gemm_grid, 256, 0, stream>>>(X16, wt16 + WT_STRIDE, H16, As, Ad, N);
  agg_kernel<false><<<agg_grid, 256, 0, stream>>>(H16, As, Ad, row_start, csr, bias[1], X16, N);
  // layer 2 (agg -> fp32 bufQ; Xa no longer needed)
  gemm_mfma<<<gemm_grid, 256, 0, stream>>>(X16, wt16 + 2 * WT_STRIDE, H16, As, Ad, N);
  agg_kernel<true><<<agg_grid, 256, 0, stream>>>(H16, As, Ad, row_start, csr, bias[2], bufQ, N);

  pool_logits<<<(N + 63) / 64, 128, 0, stream>>>(bufQ, batch, Wh, (float*)d_out, N, G);
}